// Round 2
// baseline (888.527 us; speedup 1.0000x reference)
//
#include <hip/hip_runtime.h>
#include <hip/hip_bf16.h>
#include <math.h>

// ---------------- constants ----------------
constexpr int Bc = 2, Sc = 2048, Dc = 512, Lc = 4, Vc = 32000;
constexpr int Mc = Bc * Sc;          // 4096 rows
constexpr int NCHUNK = 16;           // S chunks for scan
constexpr int CHUNK = Sc / NCHUNK;   // 128
constexpr int SEG = 32;              // s per thread in scan
constexpr float LN_EPS = 1e-5f;

typedef __attribute__((ext_vector_type(8))) short short8;   // 8 bf16
typedef __attribute__((ext_vector_type(4))) float f32x4;

// ---------------- helpers ----------------
__device__ __forceinline__ void gload_lds16(const __hip_bfloat16* g, __hip_bfloat16* l) {
    __builtin_amdgcn_global_load_lds((const __attribute__((address_space(1))) void*)g,
                                     (__attribute__((address_space(3))) void*)l, 16, 0, 0);
}

// ---------------- embedding + sinusoidal PE ----------------
__global__ __launch_bounds__(256) void embed_kernel(const int* __restrict__ tokens,
                                                    const float* __restrict__ emb,
                                                    float* __restrict__ x) {
    int row = blockIdx.x;            // b*S + s
    int s = row % Sc;
    int tok = tokens[row];
    const float* e = emb + (size_t)tok * Dc;
    float* xr = x + (size_t)row * Dc;
    const float kc = -9.210340371976184f / (float)Dc;   // -ln(10000)/D
    for (int q = 0; q < 2; ++q) {
        int d = q * 256 + threadIdx.x;
        int i = d >> 1;
        float div = expf((float)(2 * i) * kc);
        float ang = (float)s * div;
        float pe = (d & 1) ? cosf(ang) : sinf(ang);
        xr[d] = e[d] + pe;
    }
}

// ---------------- layernorm (writes f32 and/or bf16) ----------------
template<bool W32>
__global__ __launch_bounds__(256) void ln_kernel(const float* __restrict__ x,
                                                 const float* __restrict__ w,
                                                 const float* __restrict__ bb,
                                                 float* __restrict__ h32,
                                                 __hip_bfloat16* __restrict__ h16) {
    __shared__ float red[8];
    int row = blockIdx.x;
    int t = threadIdx.x;
    const float* xr = x + (size_t)row * Dc;
    float2 v = ((const float2*)xr)[t];
    float sum = v.x + v.y;
    for (int o = 32; o; o >>= 1) sum += __shfl_down(sum, o);
    if ((t & 63) == 0) red[t >> 6] = sum;
    __syncthreads();
    float mu = (red[0] + red[1] + red[2] + red[3]) * (1.f / (float)Dc);
    float d0 = v.x - mu, d1 = v.y - mu;
    float vs = d0 * d0 + d1 * d1;
    for (int o = 32; o; o >>= 1) vs += __shfl_down(vs, o);
    if ((t & 63) == 0) red[4 + (t >> 6)] = vs;
    __syncthreads();
    float var = (red[4] + red[5] + red[6] + red[7]) * (1.f / (float)Dc);
    float rstd = 1.f / sqrtf(var + LN_EPS);
    float o0 = d0 * rstd * w[2 * t] + bb[2 * t];
    float o1 = d1 * rstd * w[2 * t + 1] + bb[2 * t + 1];
    if constexpr (W32) {
        float2 hv; hv.x = o0; hv.y = o1;
        ((float2*)h32)[(size_t)row * (Dc / 2) + t] = hv;
    }
    __hip_bfloat162 hb;
    hb.x = __float2bfloat16(o0);
    hb.y = __float2bfloat16(o1);
    ((__hip_bfloat162*)h16)[(size_t)row * (Dc / 2) + t] = hb;
}

// ---------------- fp32 [R][C] -> bf16 [C][R] transpose ----------------
__global__ __launch_bounds__(256) void transpose_to_bf16(const float* __restrict__ in,
                                                         __hip_bfloat16* __restrict__ outp,
                                                         int R, int C, size_t lstride) {
    __shared__ float tile[32][33];
    const float* ip = in + (size_t)blockIdx.z * lstride;
    __hip_bfloat16* op = outp + (size_t)blockIdx.z * lstride;
    int c0 = blockIdx.x * 32, r0 = blockIdx.y * 32;
    int tx = threadIdx.x, ty = threadIdx.y;      // (32, 8)
    #pragma unroll
    for (int q = 0; q < 4; ++q) {
        int r = r0 + ty + q * 8;
        tile[ty + q * 8][tx] = ip[(size_t)r * C + c0 + tx];
    }
    __syncthreads();
    #pragma unroll
    for (int q = 0; q < 4; ++q) {
        int c = c0 + ty + q * 8;
        op[(size_t)c * R + r0 + tx] = __float2bfloat16(tile[tx][ty + q * 8]);
    }
}

// ---------------- bf16 MFMA GEMM: C[M][N] (+)= A[M][K] * Bt[N][K]^T + bias[N] ----------------
// EPI 0: C = acc + bias ; EPI 1: C += acc + bias + Hres  (Hres = layernormed h residual)
template<int EPI>
__global__ __launch_bounds__(256) void gemm_bt(const __hip_bfloat16* __restrict__ A,
                                               const __hip_bfloat16* __restrict__ Bt,
                                               const float* __restrict__ bias,
                                               const float* __restrict__ Hres,
                                               float* __restrict__ C,
                                               int M, int N, int K) {
    __shared__ __hip_bfloat16 As[128 * 32];
    __shared__ __hip_bfloat16 Bs[128 * 32];
    const int tid = threadIdx.x;
    const int lane = tid & 63;
    const int wave = tid >> 6;
    const int wr = wave >> 1, wc = wave & 1;
    const int m0 = blockIdx.y * 128;
    const int n0 = blockIdx.x * 128;
    const int fr = lane & 15, fq = lane >> 4;
    f32x4 acc[4][4] = {};
    for (int k0 = 0; k0 < K; k0 += 32) {
        #pragma unroll
        for (int q = 0; q < 2; ++q) {
            int c = q * 256 + tid;
            int row = c >> 2, cc = c & 3;
            gload_lds16(A + (size_t)(m0 + row) * K + (k0 + cc * 8), &As[c * 8]);
            gload_lds16(Bt + (size_t)(n0 + row) * K + (k0 + cc * 8), &Bs[c * 8]);
        }
        __syncthreads();
        short8 a[4], b[4];
        #pragma unroll
        for (int i = 0; i < 4; ++i) a[i] = *(const short8*)&As[(wr * 64 + i * 16 + fr) * 32 + fq * 8];
        #pragma unroll
        for (int j = 0; j < 4; ++j) b[j] = *(const short8*)&Bs[(wc * 64 + j * 16 + fr) * 32 + fq * 8];
        #pragma unroll
        for (int i = 0; i < 4; ++i)
            #pragma unroll
            for (int j = 0; j < 4; ++j)
                acc[i][j] = __builtin_amdgcn_mfma_f32_16x16x32_bf16(a[i], b[j], acc[i][j], 0, 0, 0);
        __syncthreads();
    }
    #pragma unroll
    for (int i = 0; i < 4; ++i) {
        int rowb = m0 + wr * 64 + i * 16 + fq * 4;
        #pragma unroll
        for (int j = 0; j < 4; ++j) {
            int col = n0 + wc * 64 + j * 16 + fr;
            float bv = bias[col];
            #pragma unroll
            for (int t = 0; t < 4; ++t) {
                size_t idx = (size_t)(rowb + t) * N + col;
                float v = acc[i][j][t] + bv;
                if (EPI == 1) C[idx] += v + Hres[idx]; else C[idx] = v;
            }
        }
    }
}

// ---------------- scan pass 1: per-chunk totals ----------------
// chunkTot layout: [B][NCHUNK][4][D]  (q: 0=PHI 1=Wc 2=Ws 3=Acc)
__global__ __launch_bounds__(256) void scan_pass1(const float* __restrict__ omega,
                                                  const float* __restrict__ magpre,
                                                  const float* __restrict__ h,
                                                  const float* __restrict__ iscale,
                                                  float* __restrict__ chunkTot) {
    int td = threadIdx.x;          // 0..63
    int ts = threadIdx.y;          // 0..3
    int d = blockIdx.x * 64 + td;
    int chunk = blockIdx.y;
    int b = blockIdx.z;
    int s0 = chunk * CHUNK + ts * SEG;
    size_t base = ((size_t)b * Sc + s0) * Dc + d;
    float isc = fabsf(iscale[d]);
    float phi = 0.f, swc = 0.f, sws = 0.f, sacc = 0.f;
    for (int k = 0; k < SEG; ++k) {
        size_t idx = base + (size_t)k * Dc;
        float om = omega[idx];
        float mp = magpre[idx];
        float hh = h[idx];
        phi += om * isc;
        float mag = 5.f / (1.f + expf(-mp));
        float sn, cs; sincosf(phi, &sn, &cs);
        float w = mag * hh;
        swc += w * cs; sws += w * sn; sacc += mag;
    }
    __shared__ float P[4][64], WC[4][64], WS[4][64], AC[4][64];
    P[ts][td] = phi; WC[ts][td] = swc; WS[ts][td] = sws; AC[ts][td] = sacc;
    __syncthreads();
    if (ts == 0) {
        float PHI = 0.f, wc = 0.f, ws = 0.f, ac = 0.f;
        for (int t = 0; t < 4; ++t) {
            float sp, cp; sincosf(PHI, &sp, &cp);
            wc += cp * WC[t][td] - sp * WS[t][td];
            ws += sp * WC[t][td] + cp * WS[t][td];
            ac += AC[t][td];
            PHI += P[t][td];
        }
        size_t o = (((size_t)b * NCHUNK + chunk) * 4) * Dc + d;
        chunkTot[o] = PHI; chunkTot[o + Dc] = wc; chunkTot[o + 2 * Dc] = ws; chunkTot[o + 3 * Dc] = ac;
    }
}

// ---------------- scan pass 2: exclusive carries over chunks ----------------
__global__ __launch_bounds__(256) void scan_pass2(const float* __restrict__ chunkTot,
                                                  float* __restrict__ carry) {
    int d = blockIdx.x * 256 + threadIdx.x;
    int b = blockIdx.y;
    float PHI = 0.f, UR = 0.f, UI = 0.f, AC = 0.f;
    for (int c = 0; c < NCHUNK; ++c) {
        size_t o = (((size_t)b * NCHUNK + c) * 4) * Dc + d;
        carry[o] = PHI; carry[o + Dc] = UR; carry[o + 2 * Dc] = UI; carry[o + 3 * Dc] = AC;
        float sp, cp; sincosf(PHI, &sp, &cp);
        float P = chunkTot[o], wc = chunkTot[o + Dc], ws = chunkTot[o + 2 * Dc], ac = chunkTot[o + 3 * Dc];
        UR += cp * wc - sp * ws;
        UI += sp * wc + cp * ws;
        AC += ac;
        PHI += P;
    }
}

// ---------------- scan pass 3: apply carries, write ctx (bf16) ----------------
__global__ __launch_bounds__(256) void scan_pass3(const float* __restrict__ omega,
                                                  const float* __restrict__ magpre,
                                                  const float* __restrict__ h,
                                                  const float* __restrict__ iscale,
                                                  const float* __restrict__ carry,
                                                  __hip_bfloat16* __restrict__ ctx) {
    int td = threadIdx.x;
    int ts = threadIdx.y;
    int d = blockIdx.x * 64 + td;
    int chunk = blockIdx.y;
    int b = blockIdx.z;
    int s0 = chunk * CHUNK + ts * SEG;
    size_t base = ((size_t)b * Sc + s0) * Dc + d;
    float isc = fabsf(iscale[d]);
    __shared__ float sh[4][4][64];
    // step A: segment omega-sums -> global phi at segment start
    float Ps = 0.f;
    for (int k = 0; k < SEG; ++k) Ps += omega[base + (size_t)k * Dc] * isc;
    sh[0][ts][td] = Ps;
    __syncthreads();
    size_t co = (((size_t)b * NCHUNK + chunk) * 4) * Dc + d;
    float PHI0 = carry[co];
    for (int t = 0; t < ts; ++t) PHI0 += sh[0][t][td];
    // step B: segment sums of w*cos/sin with GLOBAL phase
    float phi = PHI0, wcs = 0.f, wss = 0.f, acs = 0.f;
    for (int k = 0; k < SEG; ++k) {
        size_t idx = base + (size_t)k * Dc;
        float om = omega[idx], mp = magpre[idx], hh = h[idx];
        phi += om * isc;
        float mag = 5.f / (1.f + expf(-mp));
        float sn, cs; sincosf(phi, &sn, &cs);
        float w = mag * hh;
        wcs += w * cs; wss += w * sn; acs += mag;
    }
    __syncthreads();
    sh[1][ts][td] = wcs; sh[2][ts][td] = wss; sh[3][ts][td] = acs;
    __syncthreads();
    float UR = carry[co + Dc], UI = carry[co + 2 * Dc], AC = carry[co + 3 * Dc];
    for (int t = 0; t < ts; ++t) { UR += sh[1][t][td]; UI += sh[2][t][td]; AC += sh[3][t][td]; }
    // step C: final sweep, write ctx
    phi = PHI0;
    __hip_bfloat16* ctxp = ctx + ((size_t)b * Sc + s0) * (4 * Dc) + d;
    for (int k = 0; k < SEG; ++k) {
        size_t idx = base + (size_t)k * Dc;
        float om = omega[idx], mp = magpre[idx], hh = h[idx];
        phi += om * isc;
        float mag = 5.f / (1.f + expf(-mp));
        float sn, cs; sincosf(phi, &sn, &cs);
        float w = mag * hh;
        UR += w * cs; UI += w * sn; AC += mag;
        float inv = 1.f / (AC + 1e-8f);
        float mr = UR * inv, mi = UI * inv;
        float rr = mr * cs + mi * sn;
        float ri = mi * cs - mr * sn;
        size_t o = (size_t)k * (4 * Dc);
        ctxp[o]          = __float2bfloat16(hh * cs);
        ctxp[o + Dc]     = __float2bfloat16(hh * sn);
        ctxp[o + 2 * Dc] = __float2bfloat16(rr);
        ctxp[o + 3 * Dc] = __float2bfloat16(ri);
    }
}

// ---------------- launch ----------------
extern "C" void kernel_launch(void* const* d_in, const int* in_sizes, int n_in,
                              void* d_out, int out_size, void* d_ws, size_t ws_size,
                              hipStream_t stream) {
    const int*   tokens    = (const int*)d_in[0];
    const float* emb       = (const float*)d_in[1];
    const float* ln_w      = (const float*)d_in[2];
    const float* ln_b      = (const float*)d_in[3];
    const float* W_omega   = (const float*)d_in[4];
    const float* b_omega   = (const float*)d_in[5];
    const float* int_scale = (const float*)d_in[6];
    const float* W_mag     = (const float*)d_in[7];
    const float* b_mag     = (const float*)d_in[8];
    const float* W_out     = (const float*)d_in[9];
    const float* b_out     = (const float*)d_in[10];
    const float* fln_w     = (const float*)d_in[11];
    const float* fln_b     = (const float*)d_in[12];
    const float* W_head    = (const float*)d_in[13];
    const float* b_head    = (const float*)d_in[14];
    float* out = (float*)d_out;

    char* ws = (char*)d_ws;
    size_t off = 0;
    auto alloc = [&](size_t bytes) -> char* {
        char* p = ws + off;
        off += (bytes + 255) / 256 * 256;
        return p;
    };
    const size_t MD = (size_t)Mc * Dc;
    float* x        = (float*)alloc(MD * 4);
    float* h32      = (float*)alloc(MD * 4);
    float* omega    = (float*)alloc(MD * 4);
    float* magpre   = (float*)alloc(MD * 4);
    __hip_bfloat16* h16    = (__hip_bfloat16*)alloc(MD * 2);
    __hip_bfloat16* ctx16  = (__hip_bfloat16*)alloc(MD * 4 * 2);
    __hip_bfloat16* xln16  = (__hip_bfloat16*)alloc(MD * 2);
    float* chunkTot = (float*)alloc((size_t)Bc * NCHUNK * 4 * Dc * 4);
    float* carry    = (float*)alloc((size_t)Bc * NCHUNK * 4 * Dc * 4);
    __hip_bfloat16* Wt_om   = (__hip_bfloat16*)alloc((size_t)Lc * Dc * Dc * 2);
    __hip_bfloat16* Wt_mag  = (__hip_bfloat16*)alloc((size_t)Lc * Dc * Dc * 2);
    __hip_bfloat16* Wt_out  = (__hip_bfloat16*)alloc((size_t)Lc * Dc * 4 * Dc * 2);
    __hip_bfloat16* Wt_head = (__hip_bfloat16*)alloc((size_t)Vc * Dc * 2);

    dim3 tb(32, 8);
    // weight transposes (fp32 [R][C] -> bf16 [C][R])
    transpose_to_bf16<<<dim3(Dc / 32, Dc / 32, Lc), tb, 0, stream>>>(W_omega, Wt_om, Dc, Dc, (size_t)Dc * Dc);
    transpose_to_bf16<<<dim3(Dc / 32, Dc / 32, Lc), tb, 0, stream>>>(W_mag, Wt_mag, Dc, Dc, (size_t)Dc * Dc);
    transpose_to_bf16<<<dim3(Dc / 32, (4 * Dc) / 32, Lc), tb, 0, stream>>>(W_out, Wt_out, 4 * Dc, Dc, (size_t)4 * Dc * Dc);
    transpose_to_bf16<<<dim3(Vc / 32, Dc / 32, 1), tb, 0, stream>>>(W_head, Wt_head, Dc, Vc, 0);

    embed_kernel<<<Mc, 256, 0, stream>>>(tokens, emb, x);

    dim3 scanGrid(Dc / 64, NCHUNK, Bc);
    dim3 scanBlk(64, 4);
    for (int l = 0; l < Lc; ++l) {
        ln_kernel<true><<<Mc, 256, 0, stream>>>(x, ln_w + l * Dc, ln_b + l * Dc, h32, h16);
        gemm_bt<0><<<dim3(Dc / 128, Mc / 128), 256, 0, stream>>>(h16, Wt_om + (size_t)l * Dc * Dc, b_omega + l * Dc, nullptr, omega, Mc, Dc, Dc);
        gemm_bt<0><<<dim3(Dc / 128, Mc / 128), 256, 0, stream>>>(h16, Wt_mag + (size_t)l * Dc * Dc, b_mag + l * Dc, nullptr, magpre, Mc, Dc, Dc);
        scan_pass1<<<scanGrid, scanBlk, 0, stream>>>(omega, magpre, h32, int_scale + l * Dc, chunkTot);
        scan_pass2<<<dim3(Dc / 256, Bc), 256, 0, stream>>>(chunkTot, carry);
        scan_pass3<<<scanGrid, scanBlk, 0, stream>>>(omega, magpre, h32, int_scale + l * Dc, carry, ctx16);
        gemm_bt<1><<<dim3(Dc / 128, Mc / 128), 256, 0, stream>>>(ctx16, Wt_out + (size_t)l * Dc * 4 * Dc, b_out + l * Dc, h32, x, Mc, Dc, 4 * Dc);
    }
    ln_kernel<false><<<Mc, 256, 0, stream>>>(x, fln_w, fln_b, nullptr, xln16);
    gemm_bt<0><<<dim3(Vc / 128, Mc / 128), 256, 0, stream>>>(xln16, Wt_head, b_head, nullptr, out, Mc, Vc, Dc);
}

// Round 3
// 773.097 us; speedup vs baseline: 1.1493x; 1.1493x over previous
//
#include <hip/hip_runtime.h>
#include <hip/hip_bf16.h>
#include <math.h>

// ---------------- constants ----------------
constexpr int Bc = 2, Sc = 2048, Dc = 512, Lc = 4, Vc = 32000;
constexpr int Mc = Bc * Sc;          // 4096 rows
constexpr int NSEG = 64;             // segments per sequence
constexpr int SEG = Sc / NSEG;       // 32 s per segment
constexpr float LN_EPS = 1e-5f;

typedef __attribute__((ext_vector_type(8))) short short8;   // 8 bf16
typedef __attribute__((ext_vector_type(4))) float f32x4;

// ---------------- helpers ----------------
__device__ __forceinline__ void gload_lds16(const __hip_bfloat16* g, __hip_bfloat16* l) {
    __builtin_amdgcn_global_load_lds((const __attribute__((address_space(1))) void*)g,
                                     (__attribute__((address_space(3))) void*)l, 16, 0, 0);
}

// ---------------- embedding + sinusoidal PE ----------------
__global__ __launch_bounds__(256) void embed_kernel(const int* __restrict__ tokens,
                                                    const float* __restrict__ emb,
                                                    float* __restrict__ x) {
    int row = blockIdx.x;            // b*S + s
    int s = row % Sc;
    int tok = tokens[row];
    const float* e = emb + (size_t)tok * Dc;
    float* xr = x + (size_t)row * Dc;
    const float kc = -9.210340371976184f / (float)Dc;   // -ln(10000)/D
    for (int q = 0; q < 2; ++q) {
        int d = q * 256 + threadIdx.x;
        int i = d >> 1;
        float div = expf((float)(2 * i) * kc);
        float ang = (float)s * div;
        float pe = (d & 1) ? cosf(ang) : sinf(ang);
        xr[d] = e[d] + pe;
    }
}

// ---------------- layernorm -> bf16 ----------------
__global__ __launch_bounds__(256) void ln_kernel(const float* __restrict__ x,
                                                 const float* __restrict__ w,
                                                 const float* __restrict__ bb,
                                                 __hip_bfloat16* __restrict__ h16) {
    __shared__ float red[8];
    int row = blockIdx.x;
    int t = threadIdx.x;
    const float* xr = x + (size_t)row * Dc;
    float2 v = ((const float2*)xr)[t];
    float sum = v.x + v.y;
    for (int o = 32; o; o >>= 1) sum += __shfl_down(sum, o);
    if ((t & 63) == 0) red[t >> 6] = sum;
    __syncthreads();
    float mu = (red[0] + red[1] + red[2] + red[3]) * (1.f / (float)Dc);
    float d0 = v.x - mu, d1 = v.y - mu;
    float vs = d0 * d0 + d1 * d1;
    for (int o = 32; o; o >>= 1) vs += __shfl_down(vs, o);
    if ((t & 63) == 0) red[4 + (t >> 6)] = vs;
    __syncthreads();
    float var = (red[4] + red[5] + red[6] + red[7]) * (1.f / (float)Dc);
    float rstd = 1.f / sqrtf(var + LN_EPS);
    float o0 = d0 * rstd * w[2 * t] + bb[2 * t];
    float o1 = d1 * rstd * w[2 * t + 1] + bb[2 * t + 1];
    __hip_bfloat162 hb;
    hb.x = __float2bfloat16(o0);
    hb.y = __float2bfloat16(o1);
    ((__hip_bfloat162*)h16)[(size_t)row * (Dc / 2) + t] = hb;
}

// ---------------- fp32 [R][C] -> bf16 [C][R] transpose (separate strides) ----------------
__global__ __launch_bounds__(256) void transpose_to_bf16(const float* __restrict__ in,
                                                         __hip_bfloat16* __restrict__ outp,
                                                         int R, int C, size_t istride, size_t ostride) {
    __shared__ float tile[32][33];
    const float* ip = in + (size_t)blockIdx.z * istride;
    __hip_bfloat16* op = outp + (size_t)blockIdx.z * ostride;
    int c0 = blockIdx.x * 32, r0 = blockIdx.y * 32;
    int tx = threadIdx.x, ty = threadIdx.y;      // (32, 8)
    #pragma unroll
    for (int q = 0; q < 4; ++q) {
        int r = r0 + ty + q * 8;
        tile[ty + q * 8][tx] = ip[(size_t)r * C + c0 + tx];
    }
    __syncthreads();
    #pragma unroll
    for (int q = 0; q < 4; ++q) {
        int c = c0 + ty + q * 8;
        op[(size_t)c * R + r0 + tx] = __float2bfloat16(tile[tx][ty + q * 8]);
    }
}

// ---------------- bias pack: [L][1024] = concat(b_omega[l], b_mag[l]) ----------------
__global__ __launch_bounds__(256) void pack_bias(const float* __restrict__ bo,
                                                 const float* __restrict__ bm,
                                                 float* __restrict__ dst) {
    int l = blockIdx.x, t = threadIdx.x;
    #pragma unroll
    for (int q = 0; q < 4; ++q) {
        int i = q * 256 + t;
        dst[l * 1024 + i] = (i < 512) ? bo[l * 512 + i] : bm[l * 512 + i - 512];
    }
}

// ---------------- bf16 MFMA GEMM: C[M][N-tile=128] (+)= A[M][K] * Bt[N][K]^T + bias[N]
// BM: 128 (waves 2x2, 64x64 each) or 64 (waves 2x2, 32x64 each)
// EPI 0: C = acc + bias ; EPI 1: C += acc + bias + Hres(bf16)
template<int BM, int EPI>
__global__ __launch_bounds__(256) void gemm_bt(const __hip_bfloat16* __restrict__ A,
                                               const __hip_bfloat16* __restrict__ Bt,
                                               const float* __restrict__ bias,
                                               const __hip_bfloat16* __restrict__ Hres,
                                               float* __restrict__ C,
                                               int M, int N, int K) {
    __shared__ __hip_bfloat16 As[BM * 32];
    __shared__ __hip_bfloat16 Bs[128 * 32];
    const int tid = threadIdx.x;
    const int lane = tid & 63;
    const int wave = tid >> 6;
    const int wr = wave >> 1, wc = wave & 1;
    // XCD-aware bijective swizzle (grids are %8==0)
    int nwg = gridDim.x * gridDim.y;
    int flat = blockIdx.y * gridDim.x + blockIdx.x;
    int cpx = nwg >> 3;
    int swz = (flat & 7) * cpx + (flat >> 3);
    const int m0 = (swz / gridDim.x) * BM;
    const int n0 = (swz % gridDim.x) * 128;
    const int fr = lane & 15, fq = lane >> 4;
    constexpr int MI = BM / 32;              // fragments per wave in M: 128->4, 64->2
    constexpr int ALOADS = BM / 64;          // staging loads per thread for A
    f32x4 acc[MI][4] = {};
    for (int k0 = 0; k0 < K; k0 += 32) {
        #pragma unroll
        for (int q = 0; q < ALOADS; ++q) {
            int c = q * 256 + tid;
            int row = c >> 2, cc = c & 3;
            gload_lds16(A + (size_t)(m0 + row) * K + (k0 + cc * 8), &As[c * 8]);
        }
        #pragma unroll
        for (int q = 0; q < 2; ++q) {
            int c = q * 256 + tid;
            int row = c >> 2, cc = c & 3;
            gload_lds16(Bt + (size_t)(n0 + row) * K + (k0 + cc * 8), &Bs[c * 8]);
        }
        __syncthreads();
        short8 a[MI], b[4];
        #pragma unroll
        for (int i = 0; i < MI; ++i) a[i] = *(const short8*)&As[(wr * (BM / 2) + i * 16 + fr) * 32 + fq * 8];
        #pragma unroll
        for (int j = 0; j < 4; ++j) b[j] = *(const short8*)&Bs[(wc * 64 + j * 16 + fr) * 32 + fq * 8];
        #pragma unroll
        for (int i = 0; i < MI; ++i)
            #pragma unroll
            for (int j = 0; j < 4; ++j)
                acc[i][j] = __builtin_amdgcn_mfma_f32_16x16x32_bf16(a[i], b[j], acc[i][j], 0, 0, 0);
        __syncthreads();
    }
    #pragma unroll
    for (int i = 0; i < MI; ++i) {
        int rowb = m0 + wr * (BM / 2) + i * 16 + fq * 4;
        #pragma unroll
        for (int j = 0; j < 4; ++j) {
            int col = n0 + wc * 64 + j * 16 + fr;
            float bv = bias[col];
            #pragma unroll
            for (int t = 0; t < 4; ++t) {
                size_t idx = (size_t)(rowb + t) * N + col;
                float v = acc[i][j][t] + bv;
                if constexpr (EPI == 1) C[idx] += v + __bfloat162float(Hres[idx]);
                else C[idx] = v;
            }
        }
    }
}

// ---------------- scan pass 1: per-segment totals ----------------
// segTot layout: [B][NSEG][4][D]  (q: 0=PHI 1=Wc 2=Ws 3=Acc)
__global__ __launch_bounds__(256) void scan_pass1(const float* __restrict__ ommag,
                                                  const __hip_bfloat16* __restrict__ h16,
                                                  const float* __restrict__ iscale,
                                                  float* __restrict__ segTot) {
    int td = threadIdx.x;          // 0..63
    int ts = threadIdx.y;          // 0..3
    int d = blockIdx.x * 64 + td;
    int seg = blockIdx.y * 4 + ts;
    int b = blockIdx.z;
    size_t rbase = (size_t)b * Sc + seg * SEG;
    const float* om = ommag + rbase * 1024 + d;
    const float* mg = ommag + rbase * 1024 + 512 + d;
    const __hip_bfloat16* hp = h16 + rbase * Dc + d;
    float isc = fabsf(iscale[d]);
    float phi = 0.f, swc = 0.f, sws = 0.f, sacc = 0.f;
    for (int k = 0; k < SEG; ++k) {
        float o = om[(size_t)k * 1024];
        float mp = mg[(size_t)k * 1024];
        float hh = __bfloat162float(hp[(size_t)k * Dc]);
        phi += o * isc;
        float mag = 5.f / (1.f + expf(-mp));
        float sn, cs; sincosf(phi, &sn, &cs);
        float w = mag * hh;
        swc += w * cs; sws += w * sn; sacc += mag;
    }
    size_t o = (((size_t)b * NSEG + seg) * 4) * Dc + d;
    segTot[o] = phi; segTot[o + Dc] = swc; segTot[o + 2 * Dc] = sws; segTot[o + 3 * Dc] = sacc;
}

// ---------------- scan pass 2: exclusive carries over segments ----------------
__global__ __launch_bounds__(256) void scan_pass2(const float* __restrict__ segTot,
                                                  float* __restrict__ carry) {
    int d = blockIdx.x * 256 + threadIdx.x;
    int b = blockIdx.y;
    float PHI = 0.f, UR = 0.f, UI = 0.f, AC = 0.f;
    for (int c = 0; c < NSEG; ++c) {
        size_t o = (((size_t)b * NSEG + c) * 4) * Dc + d;
        carry[o] = PHI; carry[o + Dc] = UR; carry[o + 2 * Dc] = UI; carry[o + 3 * Dc] = AC;
        float sp, cp; sincosf(PHI, &sp, &cp);
        float P = segTot[o], wc = segTot[o + Dc], ws = segTot[o + 2 * Dc], ac = segTot[o + 3 * Dc];
        UR += cp * wc - sp * ws;
        UI += sp * wc + cp * ws;
        AC += ac;
        PHI += P;
    }
}

// ---------------- scan pass 3: single sweep with per-segment carries, write ctx ----------------
__global__ __launch_bounds__(256) void scan_pass3(const float* __restrict__ ommag,
                                                  const __hip_bfloat16* __restrict__ h16,
                                                  const float* __restrict__ iscale,
                                                  const float* __restrict__ carry,
                                                  __hip_bfloat16* __restrict__ ctx) {
    int td = threadIdx.x;
    int ts = threadIdx.y;
    int d = blockIdx.x * 64 + td;
    int seg = blockIdx.y * 4 + ts;
    int b = blockIdx.z;
    size_t rbase = (size_t)b * Sc + seg * SEG;
    const float* om = ommag + rbase * 1024 + d;
    const float* mg = ommag + rbase * 1024 + 512 + d;
    const __hip_bfloat16* hp = h16 + rbase * Dc + d;
    float isc = fabsf(iscale[d]);
    size_t co = (((size_t)b * NSEG + seg) * 4) * Dc + d;
    float phi = carry[co];
    float UR = carry[co + Dc], UI = carry[co + 2 * Dc], AC = carry[co + 3 * Dc];
    __hip_bfloat16* ctxp = ctx + rbase * (4 * Dc) + d;
    for (int k = 0; k < SEG; ++k) {
        float o = om[(size_t)k * 1024];
        float mp = mg[(size_t)k * 1024];
        float hh = __bfloat162float(hp[(size_t)k * Dc]);
        phi += o * isc;
        float mag = 5.f / (1.f + expf(-mp));
        float sn, cs; sincosf(phi, &sn, &cs);
        float w = mag * hh;
        UR += w * cs; UI += w * sn; AC += mag;
        float inv = 1.f / (AC + 1e-8f);
        float mr = UR * inv, mi = UI * inv;
        float rr = mr * cs + mi * sn;
        float ri = mi * cs - mr * sn;
        size_t oo = (size_t)k * (4 * Dc);
        ctxp[oo]          = __float2bfloat16(hh * cs);
        ctxp[oo + Dc]     = __float2bfloat16(hh * sn);
        ctxp[oo + 2 * Dc] = __float2bfloat16(rr);
        ctxp[oo + 3 * Dc] = __float2bfloat16(ri);
    }
}

// ---------------- launch ----------------
extern "C" void kernel_launch(void* const* d_in, const int* in_sizes, int n_in,
                              void* d_out, int out_size, void* d_ws, size_t ws_size,
                              hipStream_t stream) {
    const int*   tokens    = (const int*)d_in[0];
    const float* emb       = (const float*)d_in[1];
    const float* ln_w      = (const float*)d_in[2];
    const float* ln_b      = (const float*)d_in[3];
    const float* W_omega   = (const float*)d_in[4];
    const float* b_omega   = (const float*)d_in[5];
    const float* int_scale = (const float*)d_in[6];
    const float* W_mag     = (const float*)d_in[7];
    const float* b_mag     = (const float*)d_in[8];
    const float* W_out     = (const float*)d_in[9];
    const float* b_out     = (const float*)d_in[10];
    const float* fln_w     = (const float*)d_in[11];
    const float* fln_b     = (const float*)d_in[12];
    const float* W_head    = (const float*)d_in[13];
    const float* b_head    = (const float*)d_in[14];
    float* out = (float*)d_out;

    char* ws = (char*)d_ws;
    size_t off = 0;
    auto alloc = [&](size_t bytes) -> char* {
        char* p = ws + off;
        off += (bytes + 255) / 256 * 256;
        return p;
    };
    const size_t MD = (size_t)Mc * Dc;
    float* x        = (float*)alloc(MD * 4);
    float* ommag    = (float*)alloc(MD * 2 * 4);             // [M][1024] f32
    __hip_bfloat16* h16    = (__hip_bfloat16*)alloc(MD * 2);
    __hip_bfloat16* ctx16  = (__hip_bfloat16*)alloc(MD * 4 * 2);
    __hip_bfloat16* xln16  = (__hip_bfloat16*)alloc(MD * 2);
    float* segTot   = (float*)alloc((size_t)Bc * NSEG * 4 * Dc * 4);
    float* carry    = (float*)alloc((size_t)Bc * NSEG * 4 * Dc * 4);
    __hip_bfloat16* Wt_ommag = (__hip_bfloat16*)alloc((size_t)Lc * 1024 * Dc * 2);
    __hip_bfloat16* Wt_out   = (__hip_bfloat16*)alloc((size_t)Lc * Dc * 4 * Dc * 2);
    __hip_bfloat16* Wt_head  = (__hip_bfloat16*)alloc((size_t)Vc * Dc * 2);
    float* bias_ommag        = (float*)alloc((size_t)Lc * 1024 * 4);

    dim3 tb(32, 8);
    // weight transposes (fp32 [R][C] -> bf16 [C][R])
    transpose_to_bf16<<<dim3(Dc / 32, Dc / 32, Lc), tb, 0, stream>>>(W_omega, Wt_ommag, Dc, Dc, (size_t)Dc * Dc, (size_t)1024 * Dc);
    transpose_to_bf16<<<dim3(Dc / 32, Dc / 32, Lc), tb, 0, stream>>>(W_mag, Wt_ommag + (size_t)512 * Dc, Dc, Dc, (size_t)Dc * Dc, (size_t)1024 * Dc);
    transpose_to_bf16<<<dim3(Dc / 32, (4 * Dc) / 32, Lc), tb, 0, stream>>>(W_out, Wt_out, 4 * Dc, Dc, (size_t)4 * Dc * Dc, (size_t)4 * Dc * Dc);
    transpose_to_bf16<<<dim3(Vc / 32, Dc / 32, 1), tb, 0, stream>>>(W_head, Wt_head, Dc, Vc, 0, 0);
    pack_bias<<<Lc, 256, 0, stream>>>(b_omega, b_mag, bias_ommag);

    embed_kernel<<<Mc, 256, 0, stream>>>(tokens, emb, x);

    dim3 scanGrid(Dc / 64, NSEG / 4, Bc);
    dim3 scanBlk(64, 4);
    for (int l = 0; l < Lc; ++l) {
        ln_kernel<<<Mc, 256, 0, stream>>>(x, ln_w + l * Dc, ln_b + l * Dc, h16);
        gemm_bt<128, 0><<<dim3(1024 / 128, Mc / 128), 256, 0, stream>>>(
            h16, Wt_ommag + (size_t)l * 1024 * Dc, bias_ommag + l * 1024, nullptr, ommag, Mc, 1024, Dc);
        scan_pass1<<<scanGrid, scanBlk, 0, stream>>>(ommag, h16, int_scale + l * Dc, segTot);
        scan_pass2<<<dim3(Dc / 256, Bc), 256, 0, stream>>>(segTot, carry);
        scan_pass3<<<scanGrid, scanBlk, 0, stream>>>(ommag, h16, int_scale + l * Dc, carry, ctx16);
        gemm_bt<64, 1><<<dim3(Dc / 128, Mc / 64), 256, 0, stream>>>(
            ctx16, Wt_out + (size_t)l * Dc * 4 * Dc, b_out + l * Dc, h16, x, Mc, Dc, 4 * Dc);
    }
    ln_kernel<<<Mc, 256, 0, stream>>>(x, fln_w, fln_b, xln16);
    gemm_bt<128, 0><<<dim3(Vc / 128, Mc / 128), 256, 0, stream>>>(
        xln16, Wt_head, b_head, nullptr, out, Mc, Vc, Dc);
}

// Round 4
// 703.051 us; speedup vs baseline: 1.2638x; 1.0996x over previous
//
#include <hip/hip_runtime.h>
#include <hip/hip_bf16.h>
#include <math.h>

// ---------------- constants ----------------
constexpr int Bc = 2, Sc = 2048, Dc = 512, Lc = 4, Vc = 32000;
constexpr int Mc = Bc * Sc;          // 4096 rows
constexpr int NSEG = 64;             // segments per sequence
constexpr int SEG = Sc / NSEG;       // 32 s per segment
constexpr float LN_EPS = 1e-5f;

typedef __attribute__((ext_vector_type(8))) short short8;   // 8 bf16
typedef __attribute__((ext_vector_type(4))) float f32x4;

// ---------------- helpers ----------------
__device__ __forceinline__ void gload_lds16(const __hip_bfloat16* g, __hip_bfloat16* l) {
    __builtin_amdgcn_global_load_lds((const __attribute__((address_space(1))) void*)g,
                                     (__attribute__((address_space(3))) void*)l, 16, 0, 0);
}

// ---------------- embedding + sinusoidal PE ----------------
__global__ __launch_bounds__(256) void embed_kernel(const int* __restrict__ tokens,
                                                    const float* __restrict__ emb,
                                                    float* __restrict__ x) {
    int row = blockIdx.x;            // b*S + s
    int s = row % Sc;
    int tok = tokens[row];
    const float* e = emb + (size_t)tok * Dc;
    float* xr = x + (size_t)row * Dc;
    const float kc = -9.210340371976184f / (float)Dc;   // -ln(10000)/D
    for (int q = 0; q < 2; ++q) {
        int d = q * 256 + threadIdx.x;
        int i = d >> 1;
        float div = expf((float)(2 * i) * kc);
        float ang = (float)s * div;
        float pe = (d & 1) ? cosf(ang) : sinf(ang);
        xr[d] = e[d] + pe;
    }
}

// ---------------- layernorm -> bf16 ----------------
__global__ __launch_bounds__(256) void ln_kernel(const float* __restrict__ x,
                                                 const float* __restrict__ w,
                                                 const float* __restrict__ bb,
                                                 __hip_bfloat16* __restrict__ h16) {
    __shared__ float red[8];
    int row = blockIdx.x;
    int t = threadIdx.x;
    const float* xr = x + (size_t)row * Dc;
    float2 v = ((const float2*)xr)[t];
    float sum = v.x + v.y;
    for (int o = 32; o; o >>= 1) sum += __shfl_down(sum, o);
    if ((t & 63) == 0) red[t >> 6] = sum;
    __syncthreads();
    float mu = (red[0] + red[1] + red[2] + red[3]) * (1.f / (float)Dc);
    float d0 = v.x - mu, d1 = v.y - mu;
    float vs = d0 * d0 + d1 * d1;
    for (int o = 32; o; o >>= 1) vs += __shfl_down(vs, o);
    if ((t & 63) == 0) red[4 + (t >> 6)] = vs;
    __syncthreads();
    float var = (red[4] + red[5] + red[6] + red[7]) * (1.f / (float)Dc);
    float rstd = 1.f / sqrtf(var + LN_EPS);
    float o0 = d0 * rstd * w[2 * t] + bb[2 * t];
    float o1 = d1 * rstd * w[2 * t + 1] + bb[2 * t + 1];
    __hip_bfloat162 hb;
    hb.x = __float2bfloat16(o0);
    hb.y = __float2bfloat16(o1);
    ((__hip_bfloat162*)h16)[(size_t)row * (Dc / 2) + t] = hb;
}

// ---------------- fp32 [R][C] -> bf16 [C][R] transpose (separate strides) ----------------
__global__ __launch_bounds__(256) void transpose_to_bf16(const float* __restrict__ in,
                                                         __hip_bfloat16* __restrict__ outp,
                                                         int R, int C, size_t istride, size_t ostride) {
    __shared__ float tile[32][33];
    const float* ip = in + (size_t)blockIdx.z * istride;
    __hip_bfloat16* op = outp + (size_t)blockIdx.z * ostride;
    int c0 = blockIdx.x * 32, r0 = blockIdx.y * 32;
    int tx = threadIdx.x, ty = threadIdx.y;      // (32, 8)
    #pragma unroll
    for (int q = 0; q < 4; ++q) {
        int r = r0 + ty + q * 8;
        tile[ty + q * 8][tx] = ip[(size_t)r * C + c0 + tx];
    }
    __syncthreads();
    #pragma unroll
    for (int q = 0; q < 4; ++q) {
        int c = c0 + ty + q * 8;
        op[(size_t)c * R + r0 + tx] = __float2bfloat16(tile[tx][ty + q * 8]);
    }
}

// ---------------- bias pack: [L][1024] = concat(b_omega[l], b_mag[l]) ----------------
__global__ __launch_bounds__(256) void pack_bias(const float* __restrict__ bo,
                                                 const float* __restrict__ bm,
                                                 float* __restrict__ dst) {
    int l = blockIdx.x, t = threadIdx.x;
    #pragma unroll
    for (int q = 0; q < 4; ++q) {
        int i = q * 256 + t;
        dst[l * 1024 + i] = (i < 512) ? bo[l * 512 + i] : bm[l * 512 + i - 512];
    }
}

// ---------------- bf16 MFMA GEMM, BK=64, T2-swizzled LDS ----------------
// C[M][N] (+)= A[M][K] * Bt[N][K]^T + bias[N]
// EPI 0: Cf = acc + bias
// EPI 1: Cf += acc + bias + Hres(bf16)     (residual layer output)
// EPI 2: Cb = bf16(acc + bias)             (ommag output)
// LDS layout: [row][64] bf16 with element swizzle colblk ^= (row&7) applied on the
// global SOURCE during global_load_lds staging (linear LDS dest) and re-applied on
// the ds_read address (both-sides involution).
template<int BM, int EPI>
__global__ __launch_bounds__(256) void gemm_bt(const __hip_bfloat16* __restrict__ A,
                                               const __hip_bfloat16* __restrict__ Bt,
                                               const float* __restrict__ bias,
                                               const __hip_bfloat16* __restrict__ Hres,
                                               float* __restrict__ Cf,
                                               __hip_bfloat16* __restrict__ Cb,
                                               int M, int N, int K) {
    __shared__ __hip_bfloat16 As[BM * 64];
    __shared__ __hip_bfloat16 Bs[128 * 64];
    const int tid = threadIdx.x;
    const int lane = tid & 63;
    const int wave = tid >> 6;
    const int wr = wave >> 1, wc = wave & 1;
    // XCD-aware bijective swizzle (all grids are %8==0)
    int nwg = gridDim.x * gridDim.y;
    int flat = blockIdx.y * gridDim.x + blockIdx.x;
    int cpx = nwg >> 3;
    int swz = (flat & 7) * cpx + (flat >> 3);
    const int m0 = (swz / gridDim.x) * BM;
    const int n0 = (swz % gridDim.x) * 128;
    const int fr = lane & 15, fq = lane >> 4;
    constexpr int MI = BM / 32;              // M fragments per wave: 128->4, 64->2
    f32x4 acc[MI][4] = {};
    for (int k0 = 0; k0 < K; k0 += 64) {
        #pragma unroll
        for (int q = 0; q < BM / 32; ++q) {
            int c = q * 256 + tid;
            int row = c >> 3, cb = c & 7;
            int gcb = cb ^ (row & 7);
            gload_lds16(A + (size_t)(m0 + row) * K + (k0 + gcb * 8), &As[c * 8]);
        }
        #pragma unroll
        for (int q = 0; q < 4; ++q) {
            int c = q * 256 + tid;
            int row = c >> 3, cb = c & 7;
            int gcb = cb ^ (row & 7);
            gload_lds16(Bt + (size_t)(n0 + row) * K + (k0 + gcb * 8), &Bs[c * 8]);
        }
        __syncthreads();
        #pragma unroll
        for (int ks = 0; ks < 2; ++ks) {
            short8 a[MI], b[4];
            #pragma unroll
            for (int i = 0; i < MI; ++i) {
                int row = wr * (BM / 2) + i * 16 + fr;
                int sb = (ks * 4 + fq) ^ (row & 7);
                a[i] = *(const short8*)&As[row * 64 + sb * 8];
            }
            #pragma unroll
            for (int j = 0; j < 4; ++j) {
                int row = wc * 64 + j * 16 + fr;
                int sb = (ks * 4 + fq) ^ (row & 7);
                b[j] = *(const short8*)&Bs[row * 64 + sb * 8];
            }
            #pragma unroll
            for (int i = 0; i < MI; ++i)
                #pragma unroll
                for (int j = 0; j < 4; ++j)
                    acc[i][j] = __builtin_amdgcn_mfma_f32_16x16x32_bf16(a[i], b[j], acc[i][j], 0, 0, 0);
        }
        __syncthreads();
    }
    #pragma unroll
    for (int i = 0; i < MI; ++i) {
        int rowb = m0 + wr * (BM / 2) + i * 16 + fq * 4;
        #pragma unroll
        for (int j = 0; j < 4; ++j) {
            int col = n0 + wc * 64 + j * 16 + fr;
            float bv = bias[col];
            #pragma unroll
            for (int t = 0; t < 4; ++t) {
                size_t idx = (size_t)(rowb + t) * N + col;
                float v = acc[i][j][t] + bv;
                if constexpr (EPI == 0) Cf[idx] = v;
                else if constexpr (EPI == 1) Cf[idx] += v + __bfloat162float(Hres[idx]);
                else Cb[idx] = __float2bfloat16(v);
            }
        }
    }
}

// ---------------- scan pass 1: per-segment totals ----------------
// segTot layout: [B][NSEG][4][D]  (q: 0=PHI 1=Wc 2=Ws 3=Acc)
__global__ __launch_bounds__(256) void scan_pass1(const __hip_bfloat16* __restrict__ ommag,
                                                  const __hip_bfloat16* __restrict__ h16,
                                                  const float* __restrict__ iscale,
                                                  float* __restrict__ segTot) {
    int td = threadIdx.x;          // 0..63
    int ts = threadIdx.y;          // 0..3
    int d = blockIdx.x * 64 + td;
    int seg = blockIdx.y * 4 + ts;
    int b = blockIdx.z;
    size_t rbase = (size_t)b * Sc + seg * SEG;
    const __hip_bfloat16* om = ommag + rbase * 1024 + d;
    const __hip_bfloat16* mg = om + 512;
    const __hip_bfloat16* hp = h16 + rbase * Dc + d;
    float isc = fabsf(iscale[d]);
    float phi = 0.f, swc = 0.f, sws = 0.f, sacc = 0.f;
    for (int k = 0; k < SEG; ++k) {
        float o = __bfloat162float(om[(size_t)k * 1024]);
        float mp = __bfloat162float(mg[(size_t)k * 1024]);
        float hh = __bfloat162float(hp[(size_t)k * Dc]);
        phi += o * isc;
        float mag = 5.f / (1.f + expf(-mp));
        float sn, cs; sincosf(phi, &sn, &cs);
        float w = mag * hh;
        swc += w * cs; sws += w * sn; sacc += mag;
    }
    size_t o = (((size_t)b * NSEG + seg) * 4) * Dc + d;
    segTot[o] = phi; segTot[o + Dc] = swc; segTot[o + 2 * Dc] = sws; segTot[o + 3 * Dc] = sacc;
}

// ---------------- scan pass 3: lookback over segTot + single sweep, write ctx ----------------
__global__ __launch_bounds__(256) void scan_pass3(const __hip_bfloat16* __restrict__ ommag,
                                                  const __hip_bfloat16* __restrict__ h16,
                                                  const float* __restrict__ iscale,
                                                  const float* __restrict__ segTot,
                                                  __hip_bfloat16* __restrict__ ctx) {
    int td = threadIdx.x;
    int ts = threadIdx.y;
    int d = blockIdx.x * 64 + td;
    int seg = blockIdx.y * 4 + ts;
    int b = blockIdx.z;
    size_t rbase = (size_t)b * Sc + seg * SEG;
    const __hip_bfloat16* om = ommag + rbase * 1024 + d;
    const __hip_bfloat16* mg = om + 512;
    const __hip_bfloat16* hp = h16 + rbase * Dc + d;
    float isc = fabsf(iscale[d]);
    // lookback: exclusive prefix over segments [0, seg) — same order as old pass2
    float PHI = 0.f, UR = 0.f, UI = 0.f, AC = 0.f;
    for (int c = 0; c < seg; ++c) {
        size_t o = (((size_t)b * NSEG + c) * 4) * Dc + d;
        float sp, cp; sincosf(PHI, &sp, &cp);
        float P = segTot[o], wcv = segTot[o + Dc], wsv = segTot[o + 2 * Dc], acv = segTot[o + 3 * Dc];
        UR += cp * wcv - sp * wsv;
        UI += sp * wcv + cp * wsv;
        AC += acv;
        PHI += P;
    }
    float phi = PHI;
    __hip_bfloat16* ctxp = ctx + rbase * (4 * Dc) + d;
    for (int k = 0; k < SEG; ++k) {
        float o = __bfloat162float(om[(size_t)k * 1024]);
        float mp = __bfloat162float(mg[(size_t)k * 1024]);
        float hh = __bfloat162float(hp[(size_t)k * Dc]);
        phi += o * isc;
        float mag = 5.f / (1.f + expf(-mp));
        float sn, cs; sincosf(phi, &sn, &cs);
        float w = mag * hh;
        UR += w * cs; UI += w * sn; AC += mag;
        float inv = 1.f / (AC + 1e-8f);
        float mr = UR * inv, mi = UI * inv;
        float rr = mr * cs + mi * sn;
        float ri = mi * cs - mr * sn;
        size_t oo = (size_t)k * (4 * Dc);
        ctxp[oo]          = __float2bfloat16(hh * cs);
        ctxp[oo + Dc]     = __float2bfloat16(hh * sn);
        ctxp[oo + 2 * Dc] = __float2bfloat16(rr);
        ctxp[oo + 3 * Dc] = __float2bfloat16(ri);
    }
}

// ---------------- launch ----------------
extern "C" void kernel_launch(void* const* d_in, const int* in_sizes, int n_in,
                              void* d_out, int out_size, void* d_ws, size_t ws_size,
                              hipStream_t stream) {
    const int*   tokens    = (const int*)d_in[0];
    const float* emb       = (const float*)d_in[1];
    const float* ln_w      = (const float*)d_in[2];
    const float* ln_b      = (const float*)d_in[3];
    const float* W_omega   = (const float*)d_in[4];
    const float* b_omega   = (const float*)d_in[5];
    const float* int_scale = (const float*)d_in[6];
    const float* W_mag     = (const float*)d_in[7];
    const float* b_mag     = (const float*)d_in[8];
    const float* W_out     = (const float*)d_in[9];
    const float* b_out     = (const float*)d_in[10];
    const float* fln_w     = (const float*)d_in[11];
    const float* fln_b     = (const float*)d_in[12];
    const float* W_head    = (const float*)d_in[13];
    const float* b_head    = (const float*)d_in[14];
    float* out = (float*)d_out;

    char* ws = (char*)d_ws;
    size_t off = 0;
    auto alloc = [&](size_t bytes) -> char* {
        char* p = ws + off;
        off += (bytes + 255) / 256 * 256;
        return p;
    };
    const size_t MD = (size_t)Mc * Dc;
    float* x        = (float*)alloc(MD * 4);
    __hip_bfloat16* ommag16 = (__hip_bfloat16*)alloc(MD * 2 * 2);   // [M][1024] bf16
    __hip_bfloat16* h16    = (__hip_bfloat16*)alloc(MD * 2);
    __hip_bfloat16* ctx16  = (__hip_bfloat16*)alloc(MD * 4 * 2);
    __hip_bfloat16* xln16  = (__hip_bfloat16*)alloc(MD * 2);
    float* segTot   = (float*)alloc((size_t)Bc * NSEG * 4 * Dc * 4);
    __hip_bfloat16* Wt_ommag = (__hip_bfloat16*)alloc((size_t)Lc * 1024 * Dc * 2);
    __hip_bfloat16* Wt_out   = (__hip_bfloat16*)alloc((size_t)Lc * Dc * 4 * Dc * 2);
    __hip_bfloat16* Wt_head  = (__hip_bfloat16*)alloc((size_t)Vc * Dc * 2);
    float* bias_ommag        = (float*)alloc((size_t)Lc * 1024 * 4);

    dim3 tb(32, 8);
    // weight transposes (fp32 [R][C] -> bf16 [C][R])
    transpose_to_bf16<<<dim3(Dc / 32, Dc / 32, Lc), tb, 0, stream>>>(W_omega, Wt_ommag, Dc, Dc, (size_t)Dc * Dc, (size_t)1024 * Dc);
    transpose_to_bf16<<<dim3(Dc / 32, Dc / 32, Lc), tb, 0, stream>>>(W_mag, Wt_ommag + (size_t)512 * Dc, Dc, Dc, (size_t)Dc * Dc, (size_t)1024 * Dc);
    transpose_to_bf16<<<dim3(Dc / 32, (4 * Dc) / 32, Lc), tb, 0, stream>>>(W_out, Wt_out, 4 * Dc, Dc, (size_t)4 * Dc * Dc, (size_t)4 * Dc * Dc);
    transpose_to_bf16<<<dim3(Vc / 32, Dc / 32, 1), tb, 0, stream>>>(W_head, Wt_head, Dc, Vc, 0, 0);
    pack_bias<<<Lc, 256, 0, stream>>>(b_omega, b_mag, bias_ommag);

    embed_kernel<<<Mc, 256, 0, stream>>>(tokens, emb, x);

    dim3 scanGrid(Dc / 64, NSEG / 4, Bc);
    dim3 scanBlk(64, 4);
    for (int l = 0; l < Lc; ++l) {
        ln_kernel<<<Mc, 256, 0, stream>>>(x, ln_w + l * Dc, ln_b + l * Dc, h16);
        gemm_bt<128, 2><<<dim3(1024 / 128, Mc / 128), 256, 0, stream>>>(
            h16, Wt_ommag + (size_t)l * 1024 * Dc, bias_ommag + l * 1024, nullptr, nullptr, ommag16, Mc, 1024, Dc);
        scan_pass1<<<scanGrid, scanBlk, 0, stream>>>(ommag16, h16, int_scale + l * Dc, segTot);
        scan_pass3<<<scanGrid, scanBlk, 0, stream>>>(ommag16, h16, int_scale + l * Dc, segTot, ctx16);
        gemm_bt<64, 1><<<dim3(Dc / 128, Mc / 64), 256, 0, stream>>>(
            ctx16, Wt_out + (size_t)l * Dc * 4 * Dc, b_out + l * Dc, h16, x, nullptr, Mc, Dc, 4 * Dc);
    }
    ln_kernel<<<Mc, 256, 0, stream>>>(x, fln_w, fln_b, xln16);
    gemm_bt<128, 0><<<dim3(Vc / 128, Mc / 128), 256, 0, stream>>>(
        xln16, Wt_head, b_head, nullptr, out, nullptr, Mc, Vc, Dc);
}